// Round 14
// baseline (312.365 us; speedup 1.0000x reference)
//
#include <hip/hip_runtime.h>
#include <math.h>

#define B_ 16
#define H_ 224
#define W_ 224
#define HP_ 226
#define WP_ 226
#define CIN_ 3
#define COUT_ 64
#define NPIX_ (B_ * H_ * W_)      /* 802816 */
#define NPAD_ (B_ * HP_ * WP_)    /* 817216 */
#define NBLK2_ (NPIX_ / 512)      /* 1568: 2 adjacent pixels per thread */
#define MAXNORM_ 0.999f
#define MINN_ 1e-7f
#define TCL_ (1.0f - 1e-5f)
#define LCLAMP_ 3.8002012f        /* atanh(0.999) */
#define BN_EPS_ 1e-5f
#define NF_ ((float)NPIX_)
#define PADW2_ 36

typedef float v4f __attribute__((ext_vector_type(4)));

// ---------------------------------------------------------------------------
// R14. R13's tap-hoist was neutral -> tap latency is NOT the stall. The one
// invariant across R1-R13 (~125us/conv-pass, VALUBusy 20%): each thread
// consumes 432 wave-uniform weight quads via ~18 s_load-batch -> FMA-cluster
// sequences (SGPR pool ~102; one cluster's 24 quads = 96 SGPRs, so batches
// can't be hoisted), each with an lgkmcnt wait; ~3 waves/SIMD all stall on
// the same pattern. Fix: 2 ADJACENT pixels per thread (same row -> 12 shared
// tap quads), weights stay on the scalar pipe, every weight batch feeds 2x
// the FMAs -> per-pixel stall halves, wave count halves. This is R5's idea
// WITHOUT R5's confound (R5 also moved weights to the DS pipe, which is what
// made it slower). (256,2): peak live ~170 VGPR, no spill possible.
// ---------------------------------------------------------------------------
struct Acc8 { v4f v0, v1, v2, v3, v4, v5, v6, v7; };
#define EACH8(X) X(0) X(1) X(2) X(3) X(4) X(5) X(6) X(7)

// ---------------------------------------------------------------------------
// K0: x (NCHW f32) -> u0p (padded NHWC4): u0 = logmap0(projx(x)) per pixel,
// zero halo ring. atanh(t) = 0.5*log((1+t)/(1-t)) via v_log_f32.
// ---------------------------------------------------------------------------
__global__ void k0_transform(const float* __restrict__ x, float4* __restrict__ u0p) {
  int idx = blockIdx.x * 256 + threadIdx.x;
  if (idx >= NPAD_) return;
  int b = idx / (HP_ * WP_);
  int r = idx % (HP_ * WP_);
  int yp = r / WP_, xp = r % WP_;
  float4 o = make_float4(0.f, 0.f, 0.f, 0.f);
  if (yp >= 1 && yp <= H_ && xp >= 1 && xp <= W_) {
    const float* xb = x + (size_t)b * (CIN_ * H_ * W_) + (size_t)(yp - 1) * W_ + (xp - 1);
    float v0 = xb[0];
    float v1 = xb[H_ * W_];
    float v2 = xb[2 * H_ * W_];
    // projx
    float n = sqrtf(fmaf(v0, v0, fmaf(v1, v1, v2 * v2)));
    float ncl = fmaxf(n, MINN_);
    float s = fminf(1.0f, MAXNORM_ / ncl);
    float p0 = v0 * s, p1 = v1 * s, p2 = v2 * s;
    // logmap0
    float np_ = fmaxf(sqrtf(fmaf(p0, p0, fmaf(p1, p1, p2 * p2))), MINN_);
    float t = fminf(np_, TCL_);
    float ath = 0.5f * __logf(__fdividef(1.0f + t, 1.0f - t));
    float f = __fdividef(ath, np_);
    o.x = p0 * f; o.y = p1 * f; o.z = p2 * f;
  }
  u0p[idx] = o;
}

// ---- taps for an adjacent pixel pair: 12 quads (3 rows x 4 cols), hoisted --
// padded cols xx..xx+3 cover both 3x3 windows (px0 uses cols 0..2, px1 1..3).
#define LOADTAPS2()                                                          \
  int bb = px0 / (H_ * W_);                                                  \
  int rr = px0 % (H_ * W_);                                                  \
  int yy = rr / W_, xx = rr % W_;                                            \
  const float4* base = u0p + ((size_t)bb * HP_ + yy) * WP_ + xx;             \
  float4 T00 = base[0],          T01 = base[1];                              \
  float4 T02 = base[2],          T03 = base[3];                              \
  float4 T10 = base[WP_],        T11 = base[WP_ + 1];                        \
  float4 T12 = base[WP_ + 2],    T13 = base[WP_ + 3];                        \
  float4 T20 = base[2 * WP_],    T21 = base[2 * WP_ + 1];                    \
  float4 T22 = base[2 * WP_ + 2], T23 = base[2 * WP_ + 3];                   \
  __builtin_amdgcn_sched_barrier(0);

// paired half-conv: channels [h8*4, h8*4+32) for BOTH pixels. Each weight
// quad (wave-uniform constant-index -> s_load/SGPR) feeds 2 pixels' FMAs.
#define INIT2(i) { v4f bv = b4[h8 + i]; A0_.v##i = bv; A1_.v##i = bv; }
#define FMA2_X(i) { v4f w = wp[h8 + i];      A0_.v##i += in0.x * w; A1_.v##i += in1.x * w; }
#define FMA2_Y(i) { v4f w = wp[16 + h8 + i]; A0_.v##i += in0.y * w; A1_.v##i += in1.y * w; }
#define FMA2_Z(i) { v4f w = wp[32 + h8 + i]; A0_.v##i += in0.z * w; A1_.v##i += in1.z * w; }
#define TAP2(t, Ta, Tb) { float4 in0 = Ta, in1 = Tb;                         \
                          const v4f* wp = (const v4f*)(wgt + (t) * 3 * COUT_); \
                          EACH8(FMA2_X) EACH8(FMA2_Y) EACH8(FMA2_Z) }
#define CONV2_HALF(h8v, P, Q) {                                              \
  const int h8 = (h8v); const v4f* b4 = (const v4f*)bias;                    \
  Acc8& A0_ = P; Acc8& A1_ = Q;                                              \
  EACH8(INIT2)                                                               \
  TAP2(0, T00, T01) TAP2(1, T01, T02) TAP2(2, T02, T03)                      \
  TAP2(3, T10, T11) TAP2(4, T11, T12) TAP2(5, T12, T13)                      \
  TAP2(6, T20, T21) TAP2(7, T21, T22) TAP2(8, T22, T23) }

__device__ __forceinline__ v4f vshfl_xor(v4f v, int m) {
  v4f r;
  r.x = __shfl_xor(v.x, m, 64);
  r.y = __shfl_xor(v.y, m, 64);
  r.z = __shfl_xor(v.z, m, 64);
  r.w = __shfl_xor(v.w, m, 64);
  return r;
}
__device__ __forceinline__ v4f vrelu(v4f v) {
  v.x = fmaxf(v.x, 0.f); v.y = fmaxf(v.y, 0.f);
  v.z = fmaxf(v.z, 0.f); v.w = fmaxf(v.w, 0.f);
  return v;
}
__device__ __forceinline__ float hsum(v4f v) { return (v.x + v.y) + (v.z + v.w); }

#define STAGE8(a) do {                                                       \
  *(v4f*)(row + 0)  = a.v0; *(v4f*)(row + 4)  = a.v1;                        \
  *(v4f*)(row + 8)  = a.v2; *(v4f*)(row + 12) = a.v3;                        \
  *(v4f*)(row + 16) = a.v4; *(v4f*)(row + 20) = a.v5;                        \
  *(v4f*)(row + 24) = a.v6; *(v4f*)(row + 28) = a.v7;                        \
} while (0)

// ---------------------------------------------------------------------------
// K1: paired conv (two halves over 12 shared taps) + deferred clamp + stats.
// 4 stage/read rounds through the 64-row wave-private tile: A-even, A-odd,
// B-even, B-odd; transposed reads apply the pixel's clamp scale from scl.
// ---------------------------------------------------------------------------
__global__ void __launch_bounds__(256, 2)
k1_stats(const float4* __restrict__ u0p, const float* __restrict__ wgt,
         const float* __restrict__ bias, float* __restrict__ partials) {
  __shared__ __align__(16) float stg[4 * 64 * PADW2_];  // 36,864 B
  __shared__ float scl[512];                            // per-pixel clamp scale
  __shared__ float red_s[256], red_q[256];
  int tid = threadIdx.x, lane = tid & 63, wid = tid >> 6;
  int px0 = blockIdx.x * 512 + wid * 128 + 2 * lane;    // even pixel; px1 = +1
  float* row = stg + (size_t)(wid * 64 + lane) * PADW2_;
  int pr8 = lane >> 3, qi = lane & 7;
  const float* rb = stg + (size_t)wid * 64 * PADW2_ + pr8 * PADW2_ + qi * 4;
  const float* scw = scl + wid * 128;

  LOADTAPS2()
  Acc8 a0, a1;
  CONV2_HALF(0, a0, a1)
  v4f s2v0 = (v4f)0.0f, s2v1 = (v4f)0.0f;
#define SQ2(i) { s2v0 += a0.v##i * a0.v##i; s2v1 += a1.v##i * a1.v##i; }
  EACH8(SQ2)
#undef SQ2
  float s2A0 = hsum(s2v0), s2A1 = hsum(s2v1);
  STAGE8(a0);
  __builtin_amdgcn_wave_barrier();

  Acc8 c0, c1;
  CONV2_HALF(8, c0, c1)
  s2v0 = (v4f)0.0f; s2v1 = (v4f)0.0f;
#define SQ2(i) { s2v0 += c0.v##i * c0.v##i; s2v1 += c1.v##i * c1.v##i; }
  EACH8(SQ2)
#undef SQ2
  float n0 = sqrtf(s2A0 + hsum(s2v0));
  float n1 = sqrtf(s2A1 + hsum(s2v1));
  scl[wid * 128 + 2 * lane]     = (n0 > LCLAMP_) ? __fdividef(LCLAMP_, n0) : 1.0f;
  scl[wid * 128 + 2 * lane + 1] = (n1 > LCLAMP_) ? __fdividef(LCLAMP_, n1) : 1.0f;
  __builtin_amdgcn_wave_barrier();

  v4f sA = (v4f)0.0f, qA = (v4f)0.0f, sB = (v4f)0.0f, qB = (v4f)0.0f;
  // tile row r holds pixel (2r + par) of the wave's 128; read applies sc.
#define RDROUND(sv, qv, par)                                                 \
  _Pragma("unroll") for (int j = 0; j < 8; j++) {                            \
    float g = scw[2 * (j * 8 + pr8) + (par)];                                \
    v4f v = *(const v4f*)(rb + j * 8 * PADW2_) * g;                          \
    sv += v; qv += v * v;                                                    \
  }
  RDROUND(sA, qA, 0)                 // A-even (a0 staged above)
  __builtin_amdgcn_wave_barrier();
  STAGE8(a1);
  __builtin_amdgcn_wave_barrier();
  RDROUND(sA, qA, 1)                 // A-odd
  __builtin_amdgcn_wave_barrier();
  STAGE8(c0);
  __builtin_amdgcn_wave_barrier();
  RDROUND(sB, qB, 0)                 // B-even
  __builtin_amdgcn_wave_barrier();
  STAGE8(c1);
  __builtin_amdgcn_wave_barrier();
  RDROUND(sB, qB, 1)                 // B-odd
#undef RDROUND

  sA += vshfl_xor(sA, 8);  qA += vshfl_xor(qA, 8);
  sA += vshfl_xor(sA, 16); qA += vshfl_xor(qA, 16);
  sA += vshfl_xor(sA, 32); qA += vshfl_xor(qA, 32);
  sB += vshfl_xor(sB, 8);  qB += vshfl_xor(qB, 8);
  sB += vshfl_xor(sB, 16); qB += vshfl_xor(qB, 16);
  sB += vshfl_xor(sB, 32); qB += vshfl_xor(qB, 32);
  if (lane < 8) {  // lane qi holds wave-total for ch quad qi
    *(v4f*)&red_s[wid * 32 + qi * 4] = sA;
    *(v4f*)&red_q[wid * 32 + qi * 4] = qA;
    *(v4f*)&red_s[128 + wid * 32 + qi * 4] = sB;
    *(v4f*)&red_q[128 + wid * 32 + qi * 4] = qB;
  }
  __syncthreads();
  if (tid < 128) {
    int c = tid & 63;
    int base2 = (c >> 5) * 128 + (c & 31);
    const float* rr2 = (tid < 64) ? red_s : red_q;
    float tot = rr2[base2] + rr2[base2 + 32] + rr2[base2 + 64] + rr2[base2 + 96];
    // partials[blk*128 + c] = sum_c ; partials[blk*128 + 64 + c] = sumsq_c
    partials[(size_t)blockIdx.x * 128 + tid] = tot;
  }
}

// ---------------------------------------------------------------------------
// K2: 64 blocks, one per channel. Block c reduces the sum and sumsq columns
// of partials[1568][128] and writes mean[c], rstd*gamma[c].
// ---------------------------------------------------------------------------
__global__ void k2_finalize(const float* __restrict__ partials, const float* __restrict__ gamma,
                            float* __restrict__ stats) {
  int c = blockIdx.x;      // 0..63
  int t = threadIdx.x;     // 256 threads
  float s = 0.f, q = 0.f;
  for (int i = t; i < NBLK2_; i += 256) {
    s += partials[(size_t)i * 128 + c];
    q += partials[(size_t)i * 128 + 64 + c];
  }
  __shared__ float ls[256], lq[256];
  ls[t] = s; lq[t] = q;
  __syncthreads();
#pragma unroll
  for (int off = 128; off > 0; off >>= 1) {
    if (t < off) { ls[t] += ls[t + off]; lq[t] += lq[t + off]; }
    __syncthreads();
  }
  if (t == 0) {
    float mean = ls[0] / NF_;
    float msq  = lq[0] / NF_;
    float var = msq - mean * mean;            // jnp.var (ddof=0)
    stats[c] = mean;
    stats[64 + c] = gamma[c] / sqrtf(var + BN_EPS_);
  }
}

// ---------------------------------------------------------------------------
// K3: paired conv + BN, nonlinear tail folded into per-pixel g = fs*sv
// (relu(sv*u) = sv*relu(u), sv>0). 4 stage/read/store rounds; stores are
// coalesced nontemporal b128: per instruction 8 x 128B full-sector runs
// (at 512B pixel pitch for the even/odd rounds -- still full sectors).
// ---------------------------------------------------------------------------
__global__ void __launch_bounds__(256, 2)
k3_final(const float4* __restrict__ u0p, const float* __restrict__ wgt,
         const float* __restrict__ bias, const float* __restrict__ stats,
         const float* __restrict__ beta, float* __restrict__ out) {
  __shared__ __align__(16) float stg[4 * 64 * PADW2_];  // 36,864 B
  __shared__ float gl[512];                             // per-pixel out scale
  int tid = threadIdx.x, lane = tid & 63, wid = tid >> 6;
  int px0 = blockIdx.x * 512 + wid * 128 + 2 * lane;
  float* row = stg + (size_t)(wid * 64 + lane) * PADW2_;
  int pr8 = lane >> 3, qi = lane & 7;
  const float* rb = stg + (size_t)wid * 64 * PADW2_ + pr8 * PADW2_ + qi * 4;
  const float* glw = gl + wid * 128;
  v4f* ow = (v4f*)out + ((size_t)blockIdx.x * 512 + wid * 128) * 16;

  const v4f* mean4 = (const v4f*)stats;
  const v4f* rg4   = (const v4f*)(stats + 64);
  const v4f* beta4 = (const v4f*)beta;

  LOADTAPS2()
  Acc8 a0, a1;
  CONV2_HALF(0, a0, a1)
  v4f s0v = (v4f)0.0f, r0v = (v4f)0.0f, s1v = (v4f)0.0f, r1v = (v4f)0.0f;
#define BN2A(i) {                                                            \
    a0.v##i = (a0.v##i - mean4[i]) * rg4[i] + beta4[i];                      \
    s0v += a0.v##i * a0.v##i; v4f t_ = vrelu(a0.v##i); r0v += t_ * t_;       \
    a1.v##i = (a1.v##i - mean4[i]) * rg4[i] + beta4[i];                      \
    s1v += a1.v##i * a1.v##i; v4f u_ = vrelu(a1.v##i); r1v += u_ * u_; }
  EACH8(BN2A)
#undef BN2A
  float nv2_0 = hsum(s0v), r2_0 = hsum(r0v);
  float nv2_1 = hsum(s1v), r2_1 = hsum(r1v);
  STAGE8(a0);                        // raw BN'd half-A, even pixel
  __builtin_amdgcn_wave_barrier();

  Acc8 c0, c1;
  CONV2_HALF(8, c0, c1)
  s0v = (v4f)0.0f; r0v = (v4f)0.0f; s1v = (v4f)0.0f; r1v = (v4f)0.0f;
#define BN2B(i) {                                                            \
    c0.v##i = (c0.v##i - mean4[8 + i]) * rg4[8 + i] + beta4[8 + i];          \
    s0v += c0.v##i * c0.v##i; v4f t_ = vrelu(c0.v##i); r0v += t_ * t_;       \
    c1.v##i = (c1.v##i - mean4[8 + i]) * rg4[8 + i] + beta4[8 + i];          \
    s1v += c1.v##i * c1.v##i; v4f u_ = vrelu(c1.v##i); r1v += u_ * u_; }
  EACH8(BN2B)
#undef BN2B
  nv2_0 += hsum(s0v); r2_0 += hsum(r0v);
  nv2_1 += hsum(s1v); r2_1 += hsum(r1v);
#define OUTSCALE(nv2, r2, dst) {                                             \
    float nv = sqrtf(nv2);                                                   \
    float sv = (nv > LCLAMP_) ? __fdividef(LCLAMP_, nv) : 1.0f;              \
    float nw = fmaxf(sv * sqrtf(r2), MINN_);                                 \
    float e2 = __expf(2.0f * nw);                                            \
    float th = 1.0f - __fdividef(2.0f, e2 + 1.0f);                           \
    float se = __fdividef(th, nw);                                           \
    float clip = fminf(1.0f, MAXNORM_ / fmaxf(th, MINN_));                   \
    dst = se * clip * sv; }
  float g0, g1;
  OUTSCALE(nv2_0, r2_0, g0)
  OUTSCALE(nv2_1, r2_1, g1)
#undef OUTSCALE
  gl[wid * 128 + 2 * lane]     = g0;
  gl[wid * 128 + 2 * lane + 1] = g1;
  __builtin_amdgcn_wave_barrier();

  // tile row r holds pixel (2r + par); store ch-quad (choff+qi) of pixel p.
#define STROUND(par, choff)                                                  \
  _Pragma("unroll") for (int j = 0; j < 8; j++) {                            \
    int p = 2 * (j * 8 + pr8) + (par);                                       \
    float g = glw[p];                                                        \
    v4f v = vrelu(*(const v4f*)(rb + j * 8 * PADW2_)) * g;                   \
    __builtin_nontemporal_store(v, ow + (size_t)p * 16 + (choff) + qi);      \
  }
  STROUND(0, 0)                      // A-even (a0 staged above)
  __builtin_amdgcn_wave_barrier();
  STAGE8(a1);
  __builtin_amdgcn_wave_barrier();
  STROUND(1, 0)                      // A-odd
  __builtin_amdgcn_wave_barrier();
  STAGE8(c0);
  __builtin_amdgcn_wave_barrier();
  STROUND(0, 8)                      // B-even
  __builtin_amdgcn_wave_barrier();
  STAGE8(c1);
  __builtin_amdgcn_wave_barrier();
  STROUND(1, 8)                      // B-odd
#undef STROUND
}

// ---------------------------------------------------------------------------
extern "C" void kernel_launch(void* const* d_in, const int* in_sizes, int n_in,
                              void* d_out, int out_size, void* d_ws, size_t ws_size,
                              hipStream_t stream) {
  const float* x     = (const float*)d_in[0];  // [16,3,224,224]
  const float* wgt   = (const float*)d_in[1];  // [3,3,3,64] HWIO
  const float* bias  = (const float*)d_in[2];  // [64]
  const float* gamma = (const float*)d_in[3];  // [64]
  const float* beta  = (const float*)d_in[4];  // [64]
  float* out = (float*)d_out;                  // [16,224,224,64]

  char* ws = (char*)d_ws;
  float4* u0p      = (float4*)ws;                                           // 13,075,456 B
  float*  partials = (float*)(ws + (size_t)NPAD_ * 16);                     //    802,816 B
  float*  stats    = (float*)(ws + (size_t)NPAD_ * 16 + (size_t)NBLK2_ * 128 * 4); // 512 B

  hipLaunchKernelGGL(k0_transform, dim3((NPAD_ + 255) / 256), dim3(256), 0, stream, x, u0p);
  hipLaunchKernelGGL(k1_stats,     dim3(NBLK2_),              dim3(256), 0, stream, u0p, wgt, bias, partials);
  hipLaunchKernelGGL(k2_finalize,  dim3(64),                  dim3(256), 0, stream, partials, gamma, stats);
  hipLaunchKernelGGL(k3_final,     dim3(NBLK2_),              dim3(256), 0, stream, u0p, wgt, bias, stats, beta, out);
}